// Round 6
// baseline (5637.241 us; speedup 1.0000x reference)
//
#include <hip/hip_runtime.h>

// BI-LSTM (TF LSTMCell w/ projection), T=160 B=640 F=40 HID=768 PROJ=256, 3 layers x 2 dirs.
// R11: B-operand DIRECT FROM GLOBAL in fragment-major layout (skip LDS for weights).
// Evidence: gate is LDS-traffic-bound (24 LDS b128 ops/wave/iter = 288KB/CU/iter at
// 85-112 B/cy ~= 2600-3400 cy/iter vs ~465 cy MFMA). Weights are constant + layout-free:
// conv_wk/conv_wp now emit 16row x 64K "fragment units" ([kk][lane][16B], 2KB each) so a
// wave's B-fragment load is ONE coalesced global_load_dwordx4 per frag, served from the
// per-XCD L2 (weights stay resident: 2.4MB/XCD). LDS traffic halves (A-only: 8 reads +
// 4 writes); B moves to the parallel vector-mem pipe (~56 B/cy/CU = at L2 BW, co-limit).
// B loads split kk=0-before-barriers / kk=1-after to cap VGPR (~133 < 168) and hide L2
// latency under barrier + kk=0 MFMAs. R10's A register-lookahead kept. R8 c/bias
// prefetch dropped (was neutral, frees VGPRs). Two-launch structure kept (R7/R9 lessons:
// kernel-boundary sync beats in-kernel cross-XCD coherence on this chip).

typedef _Float16 h8 __attribute__((ext_vector_type(8)));
typedef float f4 __attribute__((ext_vector_type(4)));

#define T_STEPS 160
#define NB 640
#define HID 768
#define PROJ 256
#define NGATE 3072           // 4*HID

__device__ __forceinline__ float sigm(float x) { return 1.0f / (1.0f + __expf(-x)); }
__device__ __forceinline__ float tanh_fast(float x) { return 2.0f / (1.0f + __expf(-2.0f * x)) - 1.0f; }

struct GateArgs {
  const _Float16* A0[6];   // x-part source (X16 for l=0, prev-layer ring slot otherwise)
  const _Float16* A1[6];   // own h ring slot (h_{t-1} fw / h_{t+1} bw)
  const _Float16* Bw[6];   // WkT, fragment-major units (see conv_wk)
  const float*    bias[6];
  float*          cst[6];
  _Float16*       g[6];
  int w0[6];
  int lda0[6];
  int K[6];
  int act[6];
};

struct ProjArgs {
  const _Float16* G[6];    // [640][768] fp16
  const _Float16* Wp[6];   // WpT, fragment-major units
  _Float16* out[6];        // own ring write slot
  _Float16* out2[6];       // optional embed capture (layer 2, t in {0,159})
  int act[6];
};

// ---------------- gate GEMM: z = [x,h] @ WkT^T, fused bias+gates+c-update -> g ----------------
__global__ __launch_bounds__(256, 3) void gate_step(GateArgs args) {
  const int z = blockIdx.z;
  if (!args.act[z]) return;

  __shared__ __align__(16) char sm[36864];       // As [128][72] = 18.4KB; epilogue overlays zs [128][65] f32 = 33.3KB
  _Float16 (*As)[72] = (_Float16(*)[72])sm;
  float (*zs)[65] = (float(*)[65])sm;

  const _Float16* A0 = args.A0[z];
  const _Float16* A1 = args.A1[z];
  const _Float16* Bw = args.Bw[z];
  const int w0 = args.w0[z], lda0 = args.lda0[z], K = args.K[z];
  const int KI = K >> 6;
  const int n0 = blockIdx.x * 128;
  const int m0 = blockIdx.y * 128;
  const int tid = threadIdx.x;
  const int lane = tid & 63;
  const int wv = tid >> 6;         // 0..3
  const int wm = (wv & 1) * 64;    // wave covers rows [wm, wm+64), cols [wn, wn+64)
  const int wn = (wv >> 1) * 64;
  const int ntb = (n0 + wn) >> 4;  // first 16-row B-unit of this wave (+j for frag j)

  f4 acc[4][4] = {};

  const int lr = tid >> 3;          // 0..31 (handles rows lr + 32*r)
  const int lkg = (tid & 7) * 8;    // k-group 0,8,..,56

  // ---- prologue: stage A(k0=0) into registers ----
  h8 av[4];
  {
    const int gk = lkg;
    if (gk < w0) {
#pragma unroll
      for (int r = 0; r < 4; ++r)
        av[r] = *(const h8*)(A0 + (size_t)(m0 + lr + 32 * r) * lda0 + gk);
    } else {
#pragma unroll
      for (int r = 0; r < 4; ++r)
        av[r] = *(const h8*)(A1 + (size_t)(m0 + lr + 32 * r) * 256 + (gk - w0));
    }
  }

  for (int k0 = 0, ki = 0; k0 < K; k0 += 64, ++ki) {
    // B kk=0 fragments: coalesced global (L2-resident, fragment-major units)
    h8 bf0[4];
#pragma unroll
    for (int j = 0; j < 4; ++j) {
      const _Float16* u = Bw + (((size_t)(ntb + j) * KI + ki) << 10) + lane * 8;
      bf0[j] = *(const h8*)u;
    }
    __syncthreads();                 // prior iter's LDS readers done
#pragma unroll
    for (int r = 0; r < 4; ++r)      // vmcnt wait: av staged LAST iter (hidden)
      *(h8*)&As[lr + 32 * r][lkg] = av[r];
    // issue NEXT iter's A loads; latency hides under this iter's MFMAs
    if (k0 + 64 < K) {
      const int gk = k0 + 64 + lkg;
      if (gk < w0) {
#pragma unroll
        for (int r = 0; r < 4; ++r)
          av[r] = *(const h8*)(A0 + (size_t)(m0 + lr + 32 * r) * lda0 + gk);
      } else {
#pragma unroll
        for (int r = 0; r < 4; ++r)
          av[r] = *(const h8*)(A1 + (size_t)(m0 + lr + 32 * r) * 256 + (gk - w0));
      }
    }
    __syncthreads();
    // B kk=1 fragments: issue now, complete under kk=0 MFMAs
    h8 bf1[4];
#pragma unroll
    for (int j = 0; j < 4; ++j) {
      const _Float16* u = Bw + (((size_t)(ntb + j) * KI + ki) << 10) + lane * 8;
      bf1[j] = *(const h8*)(u + 512);
    }
    {
      const int kq0 = (lane >> 4) * 8;
#pragma unroll
      for (int i = 0; i < 4; ++i) {
        h8 af = *(const h8*)&As[wm + (lane & 15) + 16 * i][kq0];
#pragma unroll
        for (int j = 0; j < 4; ++j)
          acc[i][j] = __builtin_amdgcn_mfma_f32_16x16x32_f16(af, bf0[j], acc[i][j], 0, 0, 0);
      }
#pragma unroll
      for (int i = 0; i < 4; ++i) {
        h8 af = *(const h8*)&As[wm + (lane & 15) + 16 * i][kq0 + 32];
#pragma unroll
        for (int j = 0; j < 4; ++j)
          acc[i][j] = __builtin_amdgcn_mfma_f32_16x16x32_f16(af, bf1[j], acc[i][j], 0, 0, 0);
      }
    }
  }

  // epilogue: two 64-col passes through zs (16 hidden units each)
  const float* bias = args.bias[z];
  float* cstate = args.cst[z];
  _Float16* gout = args.g[z];
#pragma unroll
  for (int p = 0; p < 2; ++p) {
    __syncthreads();
    if ((wv >> 1) == p) {                   // waves owning n-half p write their acc
#pragma unroll
      for (int mi = 0; mi < 4; ++mi)
#pragma unroll
        for (int ni = 0; ni < 4; ++ni)
#pragma unroll
          for (int r = 0; r < 4; ++r) {
            int row = wm + mi * 16 + ((lane >> 4) << 2) + r;  // C/D: row=(lane>>4)*4+reg
            int col = ni * 16 + (lane & 15);                  //      col=lane&15 (0..63)
            zs[row][col] = acc[mi][ni][r];
          }
    }
    __syncthreads();
    const int u0 = (n0 + p * 64) >> 2;      // first hidden unit of this pass
#pragma unroll
    for (int it = 0; it < 8; ++it) {
      int item = it * 256 + tid;            // 128 rows x 16 units
      int row = item >> 4;
      int u = item & 15;
      float zi = zs[row][4 * u + 0] + bias[0 * HID + u0 + u];
      float zj = zs[row][4 * u + 1] + bias[1 * HID + u0 + u];
      float zf = zs[row][4 * u + 2] + bias[2 * HID + u0 + u];
      float zo = zs[row][4 * u + 3] + bias[3 * HID + u0 + u];
      size_t co = (size_t)(m0 + row) * HID + u0 + u;
      float cold = cstate[co];
      float cnew = sigm(zf + 1.0f) * cold + sigm(zi) * tanh_fast(zj);  // forget_bias=1.0
      float g = sigm(zo) * tanh_fast(cnew);
      cstate[co] = cnew;
      gout[co] = (_Float16)g;
    }
  }
}

// ---------------- projection GEMM: h = g @ WpT^T ----------------
// 64x64 tile, 256 threads, K=768; A via LDS w/ lookahead, B direct-global fragment-major.
__global__ __launch_bounds__(256) void proj_step(ProjArgs args) {
  const int z = blockIdx.z;
  if (!args.act[z]) return;

  __shared__ __align__(16) _Float16 As[64][72];

  const _Float16* A = args.G[z];
  const _Float16* B = args.Wp[z];
  const int n0 = blockIdx.x * 64;
  const int m0 = blockIdx.y * 64;
  const int tid = threadIdx.x;
  const int lane = tid & 63;
  const int wv = tid >> 6;
  const int wm = (wv & 1) * 32;
  const int wn = (wv >> 1) * 32;
  const int ntb = (n0 + wn) >> 4;

  f4 acc[2][2] = {};
  const int lr = tid >> 3;
  const int lkg = (tid & 7) * 8;

  // prologue: stage A(k0=0)
  h8 av0 = *(const h8*)(A + (size_t)(m0 + lr) * HID + lkg);
  h8 av1 = *(const h8*)(A + (size_t)(m0 + lr + 32) * HID + lkg);

  for (int k0 = 0, ki = 0; k0 < HID; k0 += 64, ++ki) {
    h8 bf0[2];
#pragma unroll
    for (int j = 0; j < 2; ++j) {
      const _Float16* u = B + (((size_t)(ntb + j) * 12 + ki) << 10) + lane * 8;
      bf0[j] = *(const h8*)u;
    }
    __syncthreads();
    *(h8*)&As[lr][lkg] = av0;
    *(h8*)&As[lr + 32][lkg] = av1;
    if (k0 + 64 < HID) {
      const int gk = k0 + 64 + lkg;
      av0 = *(const h8*)(A + (size_t)(m0 + lr) * HID + gk);
      av1 = *(const h8*)(A + (size_t)(m0 + lr + 32) * HID + gk);
    }
    __syncthreads();
    h8 bf1[2];
#pragma unroll
    for (int j = 0; j < 2; ++j) {
      const _Float16* u = B + (((size_t)(ntb + j) * 12 + ki) << 10) + lane * 8;
      bf1[j] = *(const h8*)(u + 512);
    }
    const int mr = wm + (lane & 15);
    {
      const int kq0 = (lane >> 4) * 8;
      h8 a0 = *(const h8*)&As[mr][kq0];
      h8 a1 = *(const h8*)&As[mr + 16][kq0];
      acc[0][0] = __builtin_amdgcn_mfma_f32_16x16x32_f16(a0, bf0[0], acc[0][0], 0, 0, 0);
      acc[0][1] = __builtin_amdgcn_mfma_f32_16x16x32_f16(a0, bf0[1], acc[0][1], 0, 0, 0);
      acc[1][0] = __builtin_amdgcn_mfma_f32_16x16x32_f16(a1, bf0[0], acc[1][0], 0, 0, 0);
      acc[1][1] = __builtin_amdgcn_mfma_f32_16x16x32_f16(a1, bf0[1], acc[1][1], 0, 0, 0);
      h8 a2 = *(const h8*)&As[mr][kq0 + 32];
      h8 a3 = *(const h8*)&As[mr + 16][kq0 + 32];
      acc[0][0] = __builtin_amdgcn_mfma_f32_16x16x32_f16(a2, bf1[0], acc[0][0], 0, 0, 0);
      acc[0][1] = __builtin_amdgcn_mfma_f32_16x16x32_f16(a2, bf1[1], acc[0][1], 0, 0, 0);
      acc[1][0] = __builtin_amdgcn_mfma_f32_16x16x32_f16(a3, bf1[0], acc[1][0], 0, 0, 0);
      acc[1][1] = __builtin_amdgcn_mfma_f32_16x16x32_f16(a3, bf1[1], acc[1][1], 0, 0, 0);
    }
  }

  _Float16* outp = args.out[z];
  _Float16* out2 = args.out2[z];
#pragma unroll
  for (int mi = 0; mi < 2; ++mi)
#pragma unroll
    for (int ni = 0; ni < 2; ++ni)
#pragma unroll
      for (int r = 0; r < 4; ++r) {
        int row = wm + mi * 16 + ((lane >> 4) << 2) + r;
        int col = wn + ni * 16 + (lane & 15);
        _Float16 v = (_Float16)acc[mi][ni][r];
        size_t o = (size_t)(m0 + row) * PROJ + (n0 + col);
        outp[o] = v;
        if (out2) out2[o] = v;
      }
}

// ---------------- prep kernels ----------------
__global__ void convX(const float* __restrict__ X, _Float16* __restrict__ X16, size_t total) {
  size_t i = (size_t)blockIdx.x * 256 + threadIdx.x;
  if (i >= total) return;
  int p = (int)(i & 63);
  size_t tb = i >> 6;
  float v = (p < 40) ? X[tb * 40 + p] : 0.0f;
  X16[i] = (_Float16)v;
}

// Wk fp32 [Kin+256, 3072] -> WkT fp16 fragment-major: 16-row x 64-K units of 2KB,
// unit layout [kk][lane][16B] with lane = ((k>>3)&3)*16 + (n&15), so a wave's B-frag
// load is one coalesced global_load_dwordx4. Gate-interleaved rows n'=4u+g.
// layer0 k-map: k<40 -> Wk[k]; 40..63 -> 0; 64..319 -> Wk[k-24]
__global__ void conv_wk(const float* __restrict__ Wk, _Float16* __restrict__ out,
                        int mode, int Kpad, size_t total) {
  size_t i = (size_t)blockIdx.x * 256 + threadIdx.x;
  if (i >= total) return;
  int k = (int)(i % Kpad);
  int n = (int)(i / Kpad);
  int u = n >> 2, g = n & 3;
  int col = g * HID + u;
  float v;
  if (mode == 0) {
    if (k < 40)      v = Wk[(size_t)k * NGATE + col];
    else if (k < 64) v = 0.0f;
    else             v = Wk[(size_t)(k - 24) * NGATE + col];
  } else {
    v = Wk[(size_t)k * NGATE + col];
  }
  const int KI = Kpad >> 6;
  size_t addr = (((size_t)(n >> 4) * KI + (k >> 6)) << 10)
              + (size_t)((k >> 5) & 1) * 512
              + (size_t)((((k >> 3) & 3) * 16 + (n & 15)) * 8)
              + (size_t)(k & 7);
  out[addr] = (_Float16)v;
}

// Wp fp32 [768][256] -> WpT fp16 fragment-major (rows = output cols c, K = 768)
__global__ void conv_wp(const float* __restrict__ Wp, _Float16* __restrict__ out, size_t total) {
  size_t i = (size_t)blockIdx.x * 256 + threadIdx.x;
  if (i >= total) return;
  int k = (int)(i % HID);
  int c = (int)(i / HID);
  float v = Wp[(size_t)k * PROJ + c];
  size_t addr = (((size_t)(c >> 4) * 12 + (k >> 6)) << 10)
              + (size_t)((k >> 5) & 1) * 512
              + (size_t)((((k >> 3) & 3) * 16 + (c & 15)) * 8)
              + (size_t)(k & 7);
  out[addr] = (_Float16)v;
}

// ---------------- readout ----------------
__global__ __launch_bounds__(256) void readout(const _Float16* __restrict__ E, float* __restrict__ out) {
  const size_t SL = (size_t)NB * PROJ;
  int b = blockIdx.x, tid = threadIdx.x;
  float v[2];
  float ss = 0.0f;
#pragma unroll
  for (int i = 0; i < 2; ++i) {
    int j = tid + i * 256;
    int d = j >> 8, c = j & 255;
    const _Float16* base = E + (size_t)d * 2 * SL;
    float a = (float)base[(size_t)b * PROJ + c];
    float zv = (float)base[SL + (size_t)b * PROJ + c];
    v[i] = 0.5f * (a + zv);
    ss += v[i] * v[i];
  }
#pragma unroll
  for (int off = 32; off; off >>= 1) ss += __shfl_down(ss, off);
  __shared__ float ps[4];
  if ((tid & 63) == 0) ps[tid >> 6] = ss;
  __syncthreads();
  float tot = ps[0] + ps[1] + ps[2] + ps[3];
  float nrm = rsqrtf(fmaxf(tot, 1e-12f));
  out[(size_t)b * 512 + tid] = v[0] * nrm;
  out[(size_t)b * 512 + tid + 256] = v[1] * nrm;
}

extern "C" void kernel_launch(void* const* d_in, const int* in_sizes, int n_in,
                              void* d_out, int out_size, void* d_ws, size_t ws_size,
                              hipStream_t stream) {
  (void)in_sizes; (void)n_in; (void)out_size; (void)ws_size;
  const float* X = (const float*)d_in[0];
  const float* Wk[2][3]; const float* Bi[2][3]; const float* Wp[2][3];
  for (int d = 0; d < 2; ++d)
    for (int l = 0; l < 3; ++l) {
      int base = 1 + d * 9 + l * 3;
      Wk[d][l] = (const float*)d_in[base];
      Bi[d][l] = (const float*)d_in[base + 1];
      Wp[d][l] = (const float*)d_in[base + 2];
    }

  char* ws = (char*)d_ws;
  size_t off = 0;
  auto alloc = [&](size_t bytes) -> void* {
    void* p = ws + off;
    off += (bytes + 255) & ~(size_t)255;
    return p;
  };

  const size_t SL = (size_t)NB * PROJ;    // halves per time-slot

  _Float16* X16 = (_Float16*)alloc((size_t)T_STEPS * NB * 64 * 2);
  _Float16* WkT[2][3];
  for (int d = 0; d < 2; ++d)
    for (int l = 0; l < 3; ++l)
      WkT[d][l] = (_Float16*)alloc((size_t)NGATE * (l == 0 ? 320 : 512) * 2);
  _Float16* WpT[2][3];
  for (int d = 0; d < 2; ++d)
    for (int l = 0; l < 3; ++l)
      WpT[d][l] = (_Float16*)alloc((size_t)PROJ * HID * 2);
  _Float16* Hbuf = (_Float16*)alloc(6UL * 4 * SL * 2);      // [l*2+d][4 slots][640][256]
  float* cst = (float*)alloc(6UL * NB * HID * 4);
  _Float16* gbuf = (_Float16*)alloc(6UL * NB * HID * 2);
  _Float16* embed = (_Float16*)alloc(4UL * SL * 2);         // [d][which][640][256]

  auto Hslot = [&](int l, int d, int slot) -> _Float16* {
    return Hbuf + (((size_t)(l * 2 + d) * 4) + slot) * SL;
  };

  // ---- prep ----
  {
    size_t tot = (size_t)T_STEPS * NB * 64;
    convX<<<dim3((unsigned)((tot + 255) / 256)), 256, 0, stream>>>(X, X16, tot);
  }
  for (int d = 0; d < 2; ++d)
    for (int l = 0; l < 3; ++l) {
      int Kpad = (l == 0) ? 320 : 512;
      size_t tot = (size_t)NGATE * Kpad;
      conv_wk<<<dim3((unsigned)((tot + 255) / 256)), 256, 0, stream>>>(
          Wk[d][l], WkT[d][l], (l == 0) ? 0 : 1, Kpad, tot);
      size_t totp = (size_t)PROJ * HID;
      conv_wp<<<dim3((unsigned)((totp + 255) / 256)), 256, 0, stream>>>(Wp[d][l], WpT[d][l], totp);
    }
  hipMemsetAsync(Hbuf, 0, 6UL * 4 * SL * 2, stream);        // zero rings (incl. h-init slots)
  hipMemsetAsync(cst, 0, 6UL * NB * HID * 4, stream);       // zero c state

  // ---- pipelined super-steps ----
  for (int s = 0; s <= 161; ++s) {
    GateArgs ga{};
    ProjArgs pa{};
    for (int l = 0; l < 3; ++l)
      for (int d = 0; d < 2; ++d) {
        int z = l * 2 + d;
        int t = s - l;                        // progress of layer l
        if (t < 0 || t > 159) { ga.act[z] = 0; pa.act[z] = 0; continue; }
        int tt = (d == 0) ? t : 159 - t;      // actual time index
        ga.act[z] = 1; pa.act[z] = 1;
        if (l == 0) {
          ga.A0[z] = X16 + (size_t)tt * NB * 64;
          ga.w0[z] = 64; ga.lda0[z] = 64; ga.K[z] = 320;
        } else {
          ga.A0[z] = Hslot(l - 1, d, (tt + 1) & 3);   // prev-layer output at time tt
          ga.w0[z] = 256; ga.lda0[z] = 256; ga.K[z] = 512;
        }
        int rdslot = (d == 0) ? (tt & 3) : ((tt + 2) & 3);
        ga.A1[z] = Hslot(l, d, rdslot);
        ga.Bw[z] = WkT[d][l];
        ga.bias[z] = Bi[d][l];
        ga.cst[z] = cst + (size_t)z * NB * HID;
        ga.g[z] = gbuf + (size_t)z * NB * HID;

        pa.G[z] = gbuf + (size_t)z * NB * HID;
        pa.Wp[z] = WpT[d][l];
        pa.out[z] = Hslot(l, d, (tt + 1) & 3);
        pa.out2[z] = nullptr;
        if (l == 2 && (tt == 0 || tt == 159))
          pa.out2[z] = embed + ((size_t)d * 2 + (tt == 0 ? 0 : 1)) * SL;
      }
    gate_step<<<dim3(24, 5, 6), 256, 0, stream>>>(ga);
    proj_step<<<dim3(4, 10, 6), 256, 0, stream>>>(pa);
  }

  readout<<<dim3(NB), 256, 0, stream>>>(embed, (float*)d_out);
}